// Round 4
// baseline (382.538 us; speedup 1.0000x reference)
//
#include <hip/hip_runtime.h>
#include <hip/hip_bf16.h>

#define BATCH 8192
#define IN_DIM 784
#define HID 128
#define CLS 10
#define ENSEMBLE 16
#define INTERNAL 255
#define TOTAL 511
#define KPAD 800   // 784 padded to multiple of 32 for MFMA K-steps
#define DSTRIDE 68 // dec_s row stride in halfs: 64+4 pad -> q-groups rotate banks

typedef __attribute__((ext_vector_type(8))) short short8;     // 8 bf16 (MFMA A/B frag)
typedef __attribute__((ext_vector_type(4))) float floatx4;    // MFMA C/D frag
typedef __attribute__((ext_vector_type(4))) _Float16 half4;   // 4 fp16 = 8 B

// ---- workspace layout (bytes) ----
// W1T_bf  : HID*KPAD*2        = 204800   @ 0
// nodeWbf : ENSEMBLE*256*HID*2= 1048576  @ 204800
// featsbf : BATCH*HID*2       = 2097152  @ 1253376

__device__ inline short f2bf(float f) {
  __hip_bfloat16 h = __float2bfloat16(f);
  return *reinterpret_cast<short*>(&h);
}

// K0: small fp32 -> bf16 conversions (W1 transpose+pad, nodeW pad)
__global__ void convert_kernel(const float* __restrict__ W1,
                               const float* __restrict__ nodeW,
                               __hip_bfloat16* __restrict__ W1T,
                               __hip_bfloat16* __restrict__ nWbf) {
  const int N2 = HID * KPAD;            // 102400
  const int N3 = ENSEMBLE * 256 * HID;  // 524288
  const int total = N2 + N3;
  for (int i = blockIdx.x * blockDim.x + threadIdx.x; i < total;
       i += gridDim.x * blockDim.x) {
    if (i < N2) {
      int c = i / KPAD, k = i - c * KPAD;
      float v = (k < IN_DIM) ? W1[k * HID + c] : 0.0f;  // W1T[c][k]
      W1T[i] = __float2bfloat16(v);
    } else {
      int j = i - N2;
      int t = j >> 15;
      int r = j & 32767;
      int ii = r >> 7;
      int d = r & 127;
      float v = (ii < INTERNAL) ? nodeW[(t * INTERNAL + ii) * HID + d] : 0.0f;
      nWbf[j] = __float2bfloat16(v);
    }
  }
}

// K1: featsbf = relu(X @ W1 + b1) (bf16 out) + fused prediction = feats @ W2 + b2.
// Block = 256 (4 waves) owns one 16-row m-tile; wave w owns cols [w*32, w*32+32).
__global__ __launch_bounds__(256) void feats_kernel(
    const float* __restrict__ X,
    const __hip_bfloat16* __restrict__ W1T,
    const float* __restrict__ b1,
    const float* __restrict__ W2,
    const float* __restrict__ b2,
    __hip_bfloat16* __restrict__ featsbf,
    float* __restrict__ pred_out) {
  __shared__ float feats_s[16 * HID];  // 8 KB fp32 feats tile
  __shared__ float W2s[HID * CLS];     // 5 KB
  __shared__ float b2s[CLS];

  const int tid = threadIdx.x;
  for (int i = tid; i < HID * CLS; i += 256) W2s[i] = W2[i];
  if (tid < CLS) b2s[tid] = b2[tid];

  const int wave = tid >> 6;
  const int lane = tid & 63;
  const int lo = lane & 15;
  const int q = lane >> 4;
  const int m0 = blockIdx.x * 16;
  const int cb = wave * 32;

  floatx4 acc0 = {0.f, 0.f, 0.f, 0.f};
  floatx4 acc1 = {0.f, 0.f, 0.f, 0.f};
  const short* Wp = (const short*)W1T;
  const float* Xrow = X + (size_t)(m0 + lo) * IN_DIM;

  for (int ks = 0; ks < KPAD / 32; ks++) {
    const int k0 = ks * 32 + q * 8;
    short8 a;
    if (k0 + 8 <= IN_DIM) {
      float4 x0 = *(const float4*)(Xrow + k0);
      float4 x1 = *(const float4*)(Xrow + k0 + 4);
      a[0] = f2bf(x0.x); a[1] = f2bf(x0.y); a[2] = f2bf(x0.z); a[3] = f2bf(x0.w);
      a[4] = f2bf(x1.x); a[5] = f2bf(x1.y); a[6] = f2bf(x1.z); a[7] = f2bf(x1.w);
    } else {
      a = (short8){0, 0, 0, 0, 0, 0, 0, 0};
    }
    short8 b0f = *(const short8*)(Wp + (size_t)(cb + lo) * KPAD + k0);
    short8 b1f = *(const short8*)(Wp + (size_t)(cb + 16 + lo) * KPAD + k0);
    acc0 = __builtin_amdgcn_mfma_f32_16x16x32_bf16(a, b0f, acc0, 0, 0, 0);
    acc1 = __builtin_amdgcn_mfma_f32_16x16x32_bf16(a, b1f, acc1, 0, 0, 0);
  }
#pragma unroll
  for (int nt = 0; nt < 2; nt++) {
    const floatx4 acc = nt ? acc1 : acc0;
    const int c = cb + nt * 16 + lo;  // D col = lane&15
    const float bias = b1[c];
#pragma unroll
    for (int r = 0; r < 4; r++) {
      const int rl = q * 4 + r;  // local row = quad*4 + reg
      float v = fmaxf(acc[r] + bias, 0.0f);
      featsbf[(size_t)(m0 + rl) * HID + c] = __float2bfloat16(v);
      feats_s[rl * HID + c] = v;
    }
  }
  __syncthreads();

  // fused prediction: 160 threads, thread = (row, cls)
  if (tid < 16 * CLS) {
    const int r = tid / CLS, c = tid - r * CLS;
    float acc = b2s[c];
    const float* fr = feats_s + r * HID;
#pragma unroll 8
    for (int k = 0; k < HID; k++) acc += fr[k] * W2s[k * CLS + c];
    pred_out[(size_t)(m0 + r) * CLS + c] = acc;
  }
}

// K3: fused dec-GEMM (bf16 MFMA) + sigmoid (fp16 LDS) + tree path products.
// *** DIAGNOSTIC ROUND: gridDim.y=32 -> the work is executed TWICE (second
// grid-half recomputes and rewrites bit-identical values; duplicate concurrent
// same-value writes are benign). Delta(dur_us) = true marginal cost of one
// tree pass; doubled dispatch should surface in rocprof top-5 with counters. ***
// Block = 256 (4 waves) = (tree t, 64-batch tile). LDS 34.7 KB -> 4 blocks/CU.
__global__ __launch_bounds__(256) void tree_kernel(
    const __hip_bfloat16* __restrict__ featsbf,
    const __hip_bfloat16* __restrict__ nWbf,
    const float* __restrict__ nodeb,
    float* __restrict__ out /* [16][511][8192] */) {
  __shared__ _Float16 dec_s[INTERNAL * DSTRIDE];  // heap-node-major, 64 batch + pad

  // Bijective swizzle over 4096 blocks: XCD k (=lin%8) owns nlin [512k,512k+512)
  // = 4 consecutive (tree,batch) panels; copies of each tree land on 2 XCDs.
  const int lin = blockIdx.y * gridDim.x + blockIdx.x;  // 0..4095
  const int nlin = (lin & 7) * 512 + (lin >> 3);        // bijective 0..4095
  const int t = (nlin >> 7) & 15;   // tree 0..15 (two copies)
  const int b0 = (nlin & 127) * 64; // batch tile

  const int tid = threadIdx.x;
  const int wave = tid >> 6;
  const int lane = tid & 63;
  const int lo = lane & 15;
  const int q = lane >> 4;

  const short* Fp = (const short*)featsbf;
  const short* Np = (const short*)nWbf;

  // B frags (feats tile): 4 n-tiles x 4 k-steps, reused across all m-tiles
  short8 bfr[4][4];
#pragma unroll
  for (int nt = 0; nt < 4; nt++)
#pragma unroll
    for (int ks = 0; ks < 4; ks++)
      bfr[nt][ks] =
          *(const short8*)(Fp + (size_t)(b0 + nt * 16 + lo) * HID + ks * 32 + q * 8);

#pragma unroll
  for (int mt = 0; mt < 4; mt++) {
    const int ibase = wave * 64 + mt * 16;
    floatx4 acc[4];
#pragma unroll
    for (int nt = 0; nt < 4; nt++) acc[nt] = (floatx4){0.f, 0.f, 0.f, 0.f};
#pragma unroll
    for (int ks = 0; ks < 4; ks++) {
      short8 a = *(const short8*)(Np + (size_t)(t * 256 + ibase + lo) * HID +
                                  ks * 32 + q * 8);
#pragma unroll
      for (int nt = 0; nt < 4; nt++)
        acc[nt] = __builtin_amdgcn_mfma_f32_16x16x32_bf16(a, bfr[nt][ks], acc[nt], 0, 0, 0);
    }
#pragma unroll
    for (int r = 0; r < 4; r++) {
      const int iloc = ibase + q * 4 + r;  // D row
      if (iloc < INTERNAL) {
        const float nb = nodeb[t * INTERNAL + iloc];
#pragma unroll
        for (int nt = 0; nt < 4; nt++) {
          const float sig = 1.0f / (1.0f + __expf(-(acc[nt][r] + nb)));
          dec_s[iloc * DSTRIDE + nt * 16 + lo] = (_Float16)sig;
        }
      }
    }
  }
  __syncthreads();

  const int s4 = tid >> 4;  // level-4 subtree 0..15
  const int bq = tid & 15;  // batch quad (4 elems)
  float* outT = out + (size_t)t * TOTAL * BATCH + b0 + bq * 4;

#define LOAD4(node)                                                    \
  ({                                                                   \
    half4 _h = *(const half4*)(dec_s + (node) * DSTRIDE + bq * 4);     \
    (floatx4){(float)_h[0], (float)_h[1], (float)_h[2], (float)_h[3]}; \
  })
#define NTS(node, v) \
  __builtin_nontemporal_store((v), (floatx4*)(outT + (size_t)(node) * BATCH))

  // Path to level-4 node s4 (heap 15+s4). Left child multiplies d, right 1-d.
  floatx4 d, p;
  d = LOAD4(0);
  p = (s4 & 8) ? (1.0f - d) : d;
  if (s4 == 0) NTS(0, ((floatx4){1.f, 1.f, 1.f, 1.f}));
  if ((s4 & 7) == 0) NTS(1 + (s4 >> 3), p);
  d = LOAD4(1 + (s4 >> 3));
  p = p * ((s4 & 4) ? (1.0f - d) : d);
  if ((s4 & 3) == 0) NTS(3 + (s4 >> 2), p);
  d = LOAD4(3 + (s4 >> 2));
  p = p * ((s4 & 2) ? (1.0f - d) : d);
  if ((s4 & 1) == 0) NTS(7 + (s4 >> 1), p);
  d = LOAD4(7 + (s4 >> 1));
  p = p * ((s4 & 1) ? (1.0f - d) : d);
  NTS(15 + s4, p);

  // Subtree BFS in registers; parents at rel level r-1, children 2^r wide.
  floatx4 P[8];
  P[0] = p;
  // r=1: parent heap 15+s4, children 31 + 2*s4 + i
  {
    floatx4 dv = LOAD4(15 + s4);
    floatx4 c0 = P[0] * dv, c1 = P[0] * (1.0f - dv);
    NTS(31 + 2 * s4 + 0, c0);
    NTS(31 + 2 * s4 + 1, c1);
    P[0] = c0; P[1] = c1;
  }
  // r=2: parents 31+2*s4+ip, children 63 + 4*s4 + i
  {
    floatx4 C[4];
#pragma unroll
    for (int ip = 0; ip < 2; ip++) {
      floatx4 dv = LOAD4(31 + 2 * s4 + ip);
      C[2 * ip] = P[ip] * dv;
      C[2 * ip + 1] = P[ip] * (1.0f - dv);
      NTS(63 + 4 * s4 + 2 * ip + 0, C[2 * ip]);
      NTS(63 + 4 * s4 + 2 * ip + 1, C[2 * ip + 1]);
    }
#pragma unroll
    for (int i = 0; i < 4; i++) P[i] = C[i];
  }
  // r=3: parents 63+4*s4+ip, children 127 + 8*s4 + i
  {
    floatx4 C[8];
#pragma unroll
    for (int ip = 0; ip < 4; ip++) {
      floatx4 dv = LOAD4(63 + 4 * s4 + ip);
      C[2 * ip] = P[ip] * dv;
      C[2 * ip + 1] = P[ip] * (1.0f - dv);
      NTS(127 + 8 * s4 + 2 * ip + 0, C[2 * ip]);
      NTS(127 + 8 * s4 + 2 * ip + 1, C[2 * ip + 1]);
    }
#pragma unroll
    for (int i = 0; i < 8; i++) P[i] = C[i];
  }
  // r=4 (leaves): parents 127+8*s4+ip, children 255 + 16*s4 + i; store only
  {
#pragma unroll
    for (int ip = 0; ip < 8; ip++) {
      floatx4 dv = LOAD4(127 + 8 * s4 + ip);
      NTS(255 + 16 * s4 + 2 * ip + 0, P[ip] * dv);
      NTS(255 + 16 * s4 + 2 * ip + 1, P[ip] * (1.0f - dv));
    }
  }
#undef LOAD4
#undef NTS
}

extern "C" void kernel_launch(void* const* d_in, const int* in_sizes, int n_in,
                              void* d_out, int out_size, void* d_ws, size_t ws_size,
                              hipStream_t stream) {
  const float* X = (const float*)d_in[0];
  const float* W1 = (const float*)d_in[1];
  const float* b1 = (const float*)d_in[2];
  const float* W2 = (const float*)d_in[3];
  const float* b2 = (const float*)d_in[4];
  const float* nodeW = (const float*)d_in[5];
  const float* nodeb = (const float*)d_in[6];

  float* pred_out = (float*)d_out;
  float* results_out = pred_out + BATCH * CLS;

  char* ws = (char*)d_ws;
  __hip_bfloat16* W1T = (__hip_bfloat16*)(ws + 0);
  __hip_bfloat16* nWbf = (__hip_bfloat16*)(ws + 204800);
  __hip_bfloat16* featsbf = (__hip_bfloat16*)(ws + 1253376);

  convert_kernel<<<612, 256, 0, stream>>>(W1, nodeW, W1T, nWbf);
  feats_kernel<<<BATCH / 16, 256, 0, stream>>>(X, W1T, b1, W2, b2, featsbf, pred_out);
  // DIAGNOSTIC: y=32 doubles tree work (second copy writes identical data).
  tree_kernel<<<dim3(BATCH / 64, 32), 256, 0, stream>>>(featsbf, nWbf, nodeb,
                                                        results_out);
}

// Round 5
// 326.055 us; speedup vs baseline: 1.1732x; 1.1732x over previous
//
#include <hip/hip_runtime.h>
#include <hip/hip_bf16.h>

#define BATCH 8192
#define IN_DIM 784
#define HID 128
#define CLS 10
#define ENSEMBLE 16
#define INTERNAL 255
#define TOTAL 511
#define KPAD 800   // 784 padded to multiple of 32 for MFMA K-steps
#define DSTRIDE 68 // dec_s row stride in halfs: 64+4 pad -> q-groups rotate banks

typedef __attribute__((ext_vector_type(8))) short short8;     // 8 bf16 (MFMA A/B frag)
typedef __attribute__((ext_vector_type(4))) float floatx4;    // MFMA C/D frag
typedef __attribute__((ext_vector_type(4))) _Float16 half4;   // 4 fp16 = 8 B

// ---- workspace layout (bytes) ----
// W1T_bf  : HID*KPAD*2         = 204800    @ 0
// nodeWbf : ENSEMBLE*256*HID*2 = 1048576   @ 204800
// featsbf : BATCH*HID*2        = 2097152   @ 1253376
// Xbf     : BATCH*KPAD*2       = 13107200  @ 3350528

__device__ inline short f2bf(float f) {
  __hip_bfloat16 h = __float2bfloat16(f);
  return *reinterpret_cast<short*>(&h);
}

// K0: fp32 -> bf16 conversions (W1 transpose+pad, nodeW pad, X pad).
// X is converted as short8 groups (100 groups/row of 8 bf16) so feats_kernel's
// A-fragment becomes a single 16 B load (kills the VALU cvt chain in its K-loop).
__global__ void convert_kernel(const float* __restrict__ W1,
                               const float* __restrict__ nodeW,
                               const float* __restrict__ X,
                               __hip_bfloat16* __restrict__ W1T,
                               __hip_bfloat16* __restrict__ nWbf,
                               __hip_bfloat16* __restrict__ Xbf) {
  const int N1 = HID * KPAD;            // 102400  scalar W1T tasks
  const int N2 = ENSEMBLE * 256 * HID;  // 524288  scalar nodeW tasks
  const int N3 = BATCH * (KPAD / 8);    // 819200  short8 X tasks
  const int total = N1 + N2 + N3;
  for (int i = blockIdx.x * blockDim.x + threadIdx.x; i < total;
       i += gridDim.x * blockDim.x) {
    if (i < N1) {
      int c = i / KPAD, k = i - c * KPAD;
      float v = (k < IN_DIM) ? W1[k * HID + c] : 0.0f;  // W1T[c][k]
      W1T[i] = __float2bfloat16(v);
    } else if (i < N1 + N2) {
      int j = i - N1;
      int t = j >> 15;
      int r = j & 32767;
      int ii = r >> 7;
      int d = r & 127;
      float v = (ii < INTERNAL) ? nodeW[(t * INTERNAL + ii) * HID + d] : 0.0f;
      nWbf[j] = __float2bfloat16(v);
    } else {
      int j = i - N1 - N2;          // short8 group index
      int m = j / (KPAD / 8);       // row
      int kb = j - m * (KPAD / 8);  // group in row, k0 = kb*8
      short8 o;
      if (kb * 8 + 8 <= IN_DIM) {   // kb 0..97: fully in-range
        const float* src = X + (size_t)m * IN_DIM + kb * 8;
        float4 x0 = *(const float4*)(src);
        float4 x1 = *(const float4*)(src + 4);
        o[0] = f2bf(x0.x); o[1] = f2bf(x0.y); o[2] = f2bf(x0.z); o[3] = f2bf(x0.w);
        o[4] = f2bf(x1.x); o[5] = f2bf(x1.y); o[6] = f2bf(x1.z); o[7] = f2bf(x1.w);
      } else {                      // kb 98,99: pad region (784..799)
        o = (short8){0, 0, 0, 0, 0, 0, 0, 0};
      }
      *(short8*)((short*)Xbf + (size_t)m * KPAD + kb * 8) = o;
    }
  }
}

// K1: featsbf = relu(Xbf @ W1 + b1) (bf16 out) + fused prediction = feats @ W2 + b2.
// Block = 256 (4 waves) owns one 16-row m-tile; wave w owns cols [w*32, w*32+32).
// K-loop is now pure {1 A-load, 2 B-loads, 2 MFMA} on pre-converted bf16.
__global__ __launch_bounds__(256) void feats_kernel(
    const __hip_bfloat16* __restrict__ Xbf,
    const __hip_bfloat16* __restrict__ W1T,
    const float* __restrict__ b1,
    const float* __restrict__ W2,
    const float* __restrict__ b2,
    __hip_bfloat16* __restrict__ featsbf,
    float* __restrict__ pred_out) {
  __shared__ float feats_s[16 * HID];  // 8 KB fp32 feats tile
  __shared__ float W2s[HID * CLS];     // 5 KB
  __shared__ float b2s[CLS];

  const int tid = threadIdx.x;
  for (int i = tid; i < HID * CLS; i += 256) W2s[i] = W2[i];
  if (tid < CLS) b2s[tid] = b2[tid];

  const int wave = tid >> 6;
  const int lane = tid & 63;
  const int lo = lane & 15;
  const int q = lane >> 4;
  const int m0 = blockIdx.x * 16;
  const int cb = wave * 32;

  floatx4 acc0 = {0.f, 0.f, 0.f, 0.f};
  floatx4 acc1 = {0.f, 0.f, 0.f, 0.f};
  const short* Wp = (const short*)W1T;
  const short* Xp = (const short*)Xbf + (size_t)(m0 + lo) * KPAD;

#pragma unroll 5
  for (int ks = 0; ks < KPAD / 32; ks++) {
    const int k0 = ks * 32 + q * 8;
    short8 a = *(const short8*)(Xp + k0);
    short8 b0f = *(const short8*)(Wp + (size_t)(cb + lo) * KPAD + k0);
    short8 b1f = *(const short8*)(Wp + (size_t)(cb + 16 + lo) * KPAD + k0);
    acc0 = __builtin_amdgcn_mfma_f32_16x16x32_bf16(a, b0f, acc0, 0, 0, 0);
    acc1 = __builtin_amdgcn_mfma_f32_16x16x32_bf16(a, b1f, acc1, 0, 0, 0);
  }
#pragma unroll
  for (int nt = 0; nt < 2; nt++) {
    const floatx4 acc = nt ? acc1 : acc0;
    const int c = cb + nt * 16 + lo;  // D col = lane&15
    const float bias = b1[c];
#pragma unroll
    for (int r = 0; r < 4; r++) {
      const int rl = q * 4 + r;  // local row = quad*4 + reg
      float v = fmaxf(acc[r] + bias, 0.0f);
      featsbf[(size_t)(m0 + rl) * HID + c] = __float2bfloat16(v);
      feats_s[rl * HID + c] = v;
    }
  }
  __syncthreads();

  // fused prediction: 160 threads, thread = (row, cls)
  if (tid < 16 * CLS) {
    const int r = tid / CLS, c = tid - r * CLS;
    float acc = b2s[c];
    const float* fr = feats_s + r * HID;
#pragma unroll 8
    for (int k = 0; k < HID; k++) acc += fr[k] * W2s[k * CLS + c];
    pred_out[(size_t)(m0 + r) * CLS + c] = acc;
  }
}

// K3: fused dec-GEMM (bf16 MFMA) + sigmoid (fp16 LDS) + tree path products.
// Measured R3: one full pass costs ~49 us marginal vs 43 us write-roofline ->
// this kernel is at its floor; structure frozen (64-batch tile, NT stores,
// DSTRIDE=68, bijective XCD swizzle).
__global__ __launch_bounds__(256) void tree_kernel(
    const __hip_bfloat16* __restrict__ featsbf,
    const __hip_bfloat16* __restrict__ nWbf,
    const float* __restrict__ nodeb,
    float* __restrict__ out /* [16][511][8192] */) {
  __shared__ _Float16 dec_s[INTERNAL * DSTRIDE];  // heap-node-major, 64 batch + pad

  // Bijective XCD-chunked swizzle over 2048 blocks (2048%8==0): XCD k owns
  // nlin [256k,256k+256) = 2 complete trees.
  const int lin = blockIdx.y * gridDim.x + blockIdx.x;  // 0..2047
  const int nlin = (lin & 7) * 256 + (lin >> 3);
  const int t = nlin >> 7;          // tree 0..15
  const int b0 = (nlin & 127) * 64; // batch tile

  const int tid = threadIdx.x;
  const int wave = tid >> 6;
  const int lane = tid & 63;
  const int lo = lane & 15;
  const int q = lane >> 4;

  const short* Fp = (const short*)featsbf;
  const short* Np = (const short*)nWbf;

  // B frags (feats tile): 4 n-tiles x 4 k-steps, reused across all m-tiles
  short8 bfr[4][4];
#pragma unroll
  for (int nt = 0; nt < 4; nt++)
#pragma unroll
    for (int ks = 0; ks < 4; ks++)
      bfr[nt][ks] =
          *(const short8*)(Fp + (size_t)(b0 + nt * 16 + lo) * HID + ks * 32 + q * 8);

#pragma unroll
  for (int mt = 0; mt < 4; mt++) {
    const int ibase = wave * 64 + mt * 16;
    floatx4 acc[4];
#pragma unroll
    for (int nt = 0; nt < 4; nt++) acc[nt] = (floatx4){0.f, 0.f, 0.f, 0.f};
#pragma unroll
    for (int ks = 0; ks < 4; ks++) {
      short8 a = *(const short8*)(Np + (size_t)(t * 256 + ibase + lo) * HID +
                                  ks * 32 + q * 8);
#pragma unroll
      for (int nt = 0; nt < 4; nt++)
        acc[nt] = __builtin_amdgcn_mfma_f32_16x16x32_bf16(a, bfr[nt][ks], acc[nt], 0, 0, 0);
    }
#pragma unroll
    for (int r = 0; r < 4; r++) {
      const int iloc = ibase + q * 4 + r;  // D row
      if (iloc < INTERNAL) {
        const float nb = nodeb[t * INTERNAL + iloc];
#pragma unroll
        for (int nt = 0; nt < 4; nt++) {
          const float sig = 1.0f / (1.0f + __expf(-(acc[nt][r] + nb)));
          dec_s[iloc * DSTRIDE + nt * 16 + lo] = (_Float16)sig;
        }
      }
    }
  }
  __syncthreads();

  const int s4 = tid >> 4;  // level-4 subtree 0..15
  const int bq = tid & 15;  // batch quad (4 elems)
  float* outT = out + (size_t)t * TOTAL * BATCH + b0 + bq * 4;

#define LOAD4(node)                                                    \
  ({                                                                   \
    half4 _h = *(const half4*)(dec_s + (node) * DSTRIDE + bq * 4);     \
    (floatx4){(float)_h[0], (float)_h[1], (float)_h[2], (float)_h[3]}; \
  })
#define NTS(node, v) \
  __builtin_nontemporal_store((v), (floatx4*)(outT + (size_t)(node) * BATCH))

  // Path to level-4 node s4 (heap 15+s4). Left child multiplies d, right 1-d.
  floatx4 d, p;
  d = LOAD4(0);
  p = (s4 & 8) ? (1.0f - d) : d;
  if (s4 == 0) NTS(0, ((floatx4){1.f, 1.f, 1.f, 1.f}));
  if ((s4 & 7) == 0) NTS(1 + (s4 >> 3), p);
  d = LOAD4(1 + (s4 >> 3));
  p = p * ((s4 & 4) ? (1.0f - d) : d);
  if ((s4 & 3) == 0) NTS(3 + (s4 >> 2), p);
  d = LOAD4(3 + (s4 >> 2));
  p = p * ((s4 & 2) ? (1.0f - d) : d);
  if ((s4 & 1) == 0) NTS(7 + (s4 >> 1), p);
  d = LOAD4(7 + (s4 >> 1));
  p = p * ((s4 & 1) ? (1.0f - d) : d);
  NTS(15 + s4, p);

  // Subtree BFS in registers; parents at rel level r-1, children 2^r wide.
  floatx4 P[8];
  P[0] = p;
  // r=1: parent heap 15+s4, children 31 + 2*s4 + i
  {
    floatx4 dv = LOAD4(15 + s4);
    floatx4 c0 = P[0] * dv, c1 = P[0] * (1.0f - dv);
    NTS(31 + 2 * s4 + 0, c0);
    NTS(31 + 2 * s4 + 1, c1);
    P[0] = c0; P[1] = c1;
  }
  // r=2: parents 31+2*s4+ip, children 63 + 4*s4 + i
  {
    floatx4 C[4];
#pragma unroll
    for (int ip = 0; ip < 2; ip++) {
      floatx4 dv = LOAD4(31 + 2 * s4 + ip);
      C[2 * ip] = P[ip] * dv;
      C[2 * ip + 1] = P[ip] * (1.0f - dv);
      NTS(63 + 4 * s4 + 2 * ip + 0, C[2 * ip]);
      NTS(63 + 4 * s4 + 2 * ip + 1, C[2 * ip + 1]);
    }
#pragma unroll
    for (int i = 0; i < 4; i++) P[i] = C[i];
  }
  // r=3: parents 63+4*s4+ip, children 127 + 8*s4 + i
  {
    floatx4 C[8];
#pragma unroll
    for (int ip = 0; ip < 4; ip++) {
      floatx4 dv = LOAD4(63 + 4 * s4 + ip);
      C[2 * ip] = P[ip] * dv;
      C[2 * ip + 1] = P[ip] * (1.0f - dv);
      NTS(127 + 8 * s4 + 2 * ip + 0, C[2 * ip]);
      NTS(127 + 8 * s4 + 2 * ip + 1, C[2 * ip + 1]);
    }
#pragma unroll
    for (int i = 0; i < 8; i++) P[i] = C[i];
  }
  // r=4 (leaves): parents 127+8*s4+ip, children 255 + 16*s4 + i; store only
  {
#pragma unroll
    for (int ip = 0; ip < 8; ip++) {
      floatx4 dv = LOAD4(127 + 8 * s4 + ip);
      NTS(255 + 16 * s4 + 2 * ip + 0, P[ip] * dv);
      NTS(255 + 16 * s4 + 2 * ip + 1, P[ip] * (1.0f - dv));
    }
  }
#undef LOAD4
#undef NTS
}

extern "C" void kernel_launch(void* const* d_in, const int* in_sizes, int n_in,
                              void* d_out, int out_size, void* d_ws, size_t ws_size,
                              hipStream_t stream) {
  const float* X = (const float*)d_in[0];
  const float* W1 = (const float*)d_in[1];
  const float* b1 = (const float*)d_in[2];
  const float* W2 = (const float*)d_in[3];
  const float* b2 = (const float*)d_in[4];
  const float* nodeW = (const float*)d_in[5];
  const float* nodeb = (const float*)d_in[6];

  float* pred_out = (float*)d_out;
  float* results_out = pred_out + BATCH * CLS;

  char* ws = (char*)d_ws;
  __hip_bfloat16* W1T = (__hip_bfloat16*)(ws + 0);
  __hip_bfloat16* nWbf = (__hip_bfloat16*)(ws + 204800);
  __hip_bfloat16* featsbf = (__hip_bfloat16*)(ws + 1253376);
  __hip_bfloat16* Xbf = (__hip_bfloat16*)(ws + 3350528);

  convert_kernel<<<2048, 256, 0, stream>>>(W1, nodeW, X, W1T, nWbf, Xbf);
  feats_kernel<<<BATCH / 16, 256, 0, stream>>>(Xbf, W1T, b1, W2, b2, featsbf, pred_out);
  tree_kernel<<<dim3(BATCH / 64, ENSEMBLE), 256, 0, stream>>>(featsbf, nWbf, nodeb,
                                                              results_out);
}